// Round 3
// baseline (369.357 us; speedup 1.0000x reference)
//
#include <hip/hip_runtime.h>

// x: [64, 3, 512, 512] f32. Per (b,c) slice: 128-bin histogram over [0,1]
// (torch.histc semantics), normalized by 512*512. feats [64,384] @ W^T + b,
// relu. W: [128,384], b: [128], out: [64,128] f32.
//
// Single fused kernel + 8-byte memset:
//   - 3072 blocks build per-chunk partial histograms (per-wave LDS atomics),
//     plain-store 128 uints each to d_ws (block-owned slot, no zeroing).
//   - release fence + device-scope ticket counter; the LAST 64 blocks to
//     finish become GEMM workers: spin until cnt==3072, acquire fence, then
//     each computes one out-row (256 threads, split-k=2).
//   - counter reset in-kernel by the 64th worker (nothing reads it again
//     within the call; kernel-end flush publishes zeros for next replay).
//   - hipMemsetAsync(ctl, 0, 8) each call guards against the one-time 0xAA
//     workspace poison.

#define BINS 128
#define NSLICE 192                 // B*C
#define SLICE_ELEMS 262144         // 512*512
#define CHUNKS 16
#define CHUNK_ELEMS (SLICE_ELEMS / CHUNKS)   // 16384
#define THREADS 256
#define WAVES 4
#define TOTAL_BLOCKS (NSLICE * CHUNKS)       // 3072
#define GEMM_BLOCKS 64
#define CTL_BYTES 256              // ctl area at head of ws, part[] after

__global__ __launch_bounds__(THREADS) void fused_hist_gemm(
        const float* __restrict__ x, const float* __restrict__ W,
        const float* __restrict__ bias, float* __restrict__ out,
        unsigned int* __restrict__ ctl, unsigned int* __restrict__ part) {
    __shared__ unsigned int lh[WAVES][BINS];
    __shared__ unsigned int s_ticket;
    __shared__ float h[3 * BINS];
    __shared__ float psum[2 * BINS];

    const int bid  = blockIdx.x;
    const int tid  = threadIdx.x;
    const int wave = tid >> 6;

    for (int i = tid; i < WAVES * BINS; i += THREADS)
        ((unsigned int*)lh)[i] = 0u;
    __syncthreads();

    // ---- phase 1: partial histogram of this chunk ----
    const float4* __restrict__ x4 = (const float4*)x;
    const int n4    = CHUNK_ELEMS >> 2;   // 4096
    const int base4 = bid * n4;
#pragma unroll 4
    for (int i = tid; i < n4; i += THREADS) {
        float4 v = x4[base4 + i];
        float vv[4] = {v.x, v.y, v.z, v.w};
#pragma unroll
        for (int j = 0; j < 4; ++j) {
            float f = vv[j];
            if (f >= 0.0f && f <= 1.0f) {
                int idx = (int)(f * (float)BINS);   // exact pow2 mul; trunc==floor
                if (idx > BINS - 1) idx = BINS - 1; // f==1.0 -> last bin
                atomicAdd(&lh[wave][idx], 1u);
            }
        }
    }
    __syncthreads();

    if (tid < BINS) {
        unsigned int s = lh[0][tid] + lh[1][tid] + lh[2][tid] + lh[3][tid];
        part[bid * BINS + tid] = s;       // plain store, block-owned slot
    }
    __syncthreads();
    __threadfence();                      // release partial stores agent-wide
    if (tid == 0)
        s_ticket = __hip_atomic_fetch_add(&ctl[0], 1u, __ATOMIC_ACQ_REL,
                                          __HIP_MEMORY_SCOPE_AGENT);
    __syncthreads();
    const unsigned int ticket = s_ticket;
    if (ticket < TOTAL_BLOCKS - GEMM_BLOCKS) return;

    // ---- phase 2: last 64 finishers do the GEMM ----
    const int b = (int)(ticket - (TOTAL_BLOCKS - GEMM_BLOCKS));  // 0..63

    if (tid == 0) {
        while (__hip_atomic_load(&ctl[0], __ATOMIC_ACQUIRE,
                                 __HIP_MEMORY_SCOPE_AGENT) < TOTAL_BLOCKS)
            __builtin_amdgcn_s_sleep(2);
    }
    __syncthreads();
    __threadfence();                      // acquire: drop stale cache lines

    const float inv = 1.0f / (float)SLICE_ELEMS;
    for (int k = tid; k < 3 * BINS; k += THREADS) {
        const int slice = b * 3 + (k >> 7);
        const int bin   = k & (BINS - 1);
        const unsigned int* __restrict__ p =
            part + (size_t)slice * CHUNKS * BINS + bin;
        unsigned int s = 0;
#pragma unroll
        for (int c = 0; c < CHUNKS; ++c)
            s += p[c * BINS];             // lanes consecutive -> coalesced
        h[k] = (float)s * inv;
    }
    __syncthreads();

    const int n    = tid & (BINS - 1);
    const int half = tid >> 7;            // split-k: 2 threads per output
    float acc = 0.0f;
    const float4* __restrict__ Wr = (const float4*)(W + n * 3 * BINS + half * 192);
    const float* __restrict__ hh  = h + half * 192;
#pragma unroll 8
    for (int k4 = 0; k4 < 48; ++k4) {
        float4 w = Wr[k4];
        acc += w.x * hh[4 * k4 + 0] + w.y * hh[4 * k4 + 1] +
               w.z * hh[4 * k4 + 2] + w.w * hh[4 * k4 + 3];
    }
    psum[tid] = acc;
    __syncthreads();
    if (tid < BINS)
        out[b * BINS + tid] = fmaxf(psum[tid] + psum[tid + BINS] + bias[tid], 0.0f);

    __syncthreads();
    if (tid == 0) {
        unsigned int t2 = __hip_atomic_fetch_add(&ctl[1], 1u, __ATOMIC_ACQ_REL,
                                                 __HIP_MEMORY_SCOPE_AGENT);
        if (t2 == GEMM_BLOCKS - 1) {      // all workers passed the gate
            __hip_atomic_store(&ctl[0], 0u, __ATOMIC_RELAXED, __HIP_MEMORY_SCOPE_AGENT);
            __hip_atomic_store(&ctl[1], 0u, __ATOMIC_RELAXED, __HIP_MEMORY_SCOPE_AGENT);
        }
    }
}

// ---- fallback: proven R2 two-kernel path (ws too small) ----

__global__ __launch_bounds__(THREADS) void hist_part(const float* __restrict__ x,
                                                     unsigned int* __restrict__ part) {
    __shared__ unsigned int lh[WAVES][BINS];
    const int bid = blockIdx.x, tid = threadIdx.x, wave = tid >> 6;
    for (int i = tid; i < WAVES * BINS; i += THREADS)
        ((unsigned int*)lh)[i] = 0u;
    __syncthreads();
    const float4* __restrict__ x4 = (const float4*)x;
    const int n4 = CHUNK_ELEMS >> 2, base4 = bid * n4;
#pragma unroll 4
    for (int i = tid; i < n4; i += THREADS) {
        float4 v = x4[base4 + i];
        float vv[4] = {v.x, v.y, v.z, v.w};
#pragma unroll
        for (int j = 0; j < 4; ++j) {
            float f = vv[j];
            if (f >= 0.0f && f <= 1.0f) {
                int idx = (int)(f * (float)BINS);
                if (idx > BINS - 1) idx = BINS - 1;
                atomicAdd(&lh[wave][idx], 1u);
            }
        }
    }
    __syncthreads();
    if (tid < BINS)
        part[bid * BINS + tid] = lh[0][tid] + lh[1][tid] + lh[2][tid] + lh[3][tid];
}

__global__ __launch_bounds__(128) void reduce_gemm(const unsigned int* __restrict__ part,
                                                   const float* __restrict__ W,
                                                   const float* __restrict__ bias,
                                                   float* __restrict__ out) {
    const int b = blockIdx.x, n = threadIdx.x;
    __shared__ float h[3 * BINS];
    const float inv = 1.0f / (float)SLICE_ELEMS;
    for (int k = n; k < 3 * BINS; k += 128) {
        const int slice = b * 3 + (k >> 7);
        const int bin   = k & (BINS - 1);
        const unsigned int* __restrict__ p = part + (size_t)slice * CHUNKS * BINS + bin;
        unsigned int s = 0;
#pragma unroll
        for (int c = 0; c < CHUNKS; ++c) s += p[c * BINS];
        h[k] = (float)s * inv;
    }
    __syncthreads();
    float acc = bias[n];
    const float4* __restrict__ Wr = (const float4*)(W + n * 3 * BINS);
#pragma unroll 8
    for (int k4 = 0; k4 < 96; ++k4) {
        float4 w = Wr[k4];
        acc += w.x * h[4 * k4 + 0] + w.y * h[4 * k4 + 1] +
               w.z * h[4 * k4 + 2] + w.w * h[4 * k4 + 3];
    }
    out[b * 128 + n] = fmaxf(acc, 0.0f);
}

extern "C" void kernel_launch(void* const* d_in, const int* in_sizes, int n_in,
                              void* d_out, int out_size, void* d_ws, size_t ws_size,
                              hipStream_t stream) {
    const float* x    = (const float*)d_in[0];
    const float* W    = (const float*)d_in[1];
    const float* bias = (const float*)d_in[2];
    float* out        = (float*)d_out;

    const size_t part_bytes = (size_t)TOTAL_BLOCKS * BINS * sizeof(unsigned int); // 1.57 MB
    if (ws_size >= CTL_BYTES + part_bytes) {
        unsigned int* ctl  = (unsigned int*)d_ws;
        unsigned int* part = (unsigned int*)((char*)d_ws + CTL_BYTES);
        hipMemsetAsync(ctl, 0, 8, stream);
        fused_hist_gemm<<<TOTAL_BLOCKS, THREADS, 0, stream>>>(x, W, bias, out, ctl, part);
    } else {
        unsigned int* part = (unsigned int*)d_ws;
        hist_part<<<TOTAL_BLOCKS, THREADS, 0, stream>>>(x, part);
        reduce_gemm<<<64, 128, 0, stream>>>(part, W, bias, out);
    }
}

// Round 4
// 41.785 us; speedup vs baseline: 8.8394x; 8.8394x over previous
//
#include <hip/hip_runtime.h>

// x: [64, 3, 512, 512] f32. Per (b,c) slice: 128-bin histogram over [0,1]
// (torch.histc semantics), normalized by 512*512. feats [64,384] @ W^T + b,
// relu. W: [128,384], b: [128], out: [64,128] f32.
//
// Two dispatches (proven R2 structure; R3's fused single-dispatch regressed
// 8x from per-block agent-scope fence cost — kernel boundary is the cheap
// cross-block flush):
//   1) hist_part: 1536 blocks (6/CU, all co-resident), per-wave LDS atomic
//      histograms, plain-store 128 uints per block (block-owned slot, no
//      zeroing needed across graph replays).
//   2) reduce_gemm: 64 blocks x 256 thr, split-k=2; sum 8 partials/slice,
//      normalize, dot with W, +bias, relu.

#define BINS 128
#define NSLICE 192                 // B*C
#define SLICE_ELEMS 262144         // 512*512
#define CHUNKS 8
#define CHUNK_ELEMS (SLICE_ELEMS / CHUNKS)   // 32768
#define THREADS 256
#define WAVES 4
#define TOTAL_BLOCKS (NSLICE * CHUNKS)       // 1536

__global__ __launch_bounds__(THREADS) void hist_part(const float* __restrict__ x,
                                                     unsigned int* __restrict__ part) {
    __shared__ unsigned int lh[WAVES][BINS];

    const int bid  = blockIdx.x;           // slice*CHUNKS + chunk
    const int tid  = threadIdx.x;
    const int wave = tid >> 6;

    for (int i = tid; i < WAVES * BINS; i += THREADS)
        ((unsigned int*)lh)[i] = 0u;
    __syncthreads();

    const float4* __restrict__ x4 = (const float4*)x;
    const int n4    = CHUNK_ELEMS >> 2;    // 8192 float4 per chunk
    const int base4 = bid * n4;
#pragma unroll 8
    for (int i = tid; i < n4; i += THREADS) {   // 32 iters/thread
        float4 v = x4[base4 + i];
        float vv[4] = {v.x, v.y, v.z, v.w};
#pragma unroll
        for (int j = 0; j < 4; ++j) {
            float f = vv[j];
            if (f >= 0.0f && f <= 1.0f) {
                int idx = (int)(f * (float)BINS);   // exact pow2 mul; trunc==floor
                if (idx > BINS - 1) idx = BINS - 1; // f==1.0 -> last bin
                atomicAdd(&lh[wave][idx], 1u);
            }
        }
    }
    __syncthreads();

    if (tid < BINS) {
        unsigned int s = lh[0][tid] + lh[1][tid] + lh[2][tid] + lh[3][tid];
        part[bid * BINS + tid] = s;        // plain store: block owns this slot
    }
}

__global__ __launch_bounds__(THREADS) void reduce_gemm(const unsigned int* __restrict__ part,
                                                       const float* __restrict__ W,
                                                       const float* __restrict__ bias,
                                                       float* __restrict__ out) {
    const int b   = blockIdx.x;    // 0..63
    const int tid = threadIdx.x;   // 0..255

    __shared__ float h[3 * BINS];          // 384
    __shared__ float psum[2 * BINS];       // 256

    const float inv = 1.0f / (float)SLICE_ELEMS;
    for (int k = tid; k < 3 * BINS; k += THREADS) {
        const int slice = b * 3 + (k >> 7);
        const int bin   = k & (BINS - 1);
        const unsigned int* __restrict__ p =
            part + (size_t)slice * CHUNKS * BINS + bin;
        unsigned int s = 0;
#pragma unroll
        for (int c = 0; c < CHUNKS; ++c)
            s += p[c * BINS];              // lanes consecutive -> coalesced
        h[k] = (float)s * inv;
    }
    __syncthreads();

    const int n    = tid & (BINS - 1);
    const int half = tid >> 7;             // split-k: 2 threads per output
    float acc = 0.0f;
    const float4* __restrict__ Wr = (const float4*)(W + n * 3 * BINS + half * 192);
    const float* __restrict__ hh  = h + half * 192;
#pragma unroll 8
    for (int k4 = 0; k4 < 48; ++k4) {
        float4 w = Wr[k4];
        acc += w.x * hh[4 * k4 + 0] + w.y * hh[4 * k4 + 1] +
               w.z * hh[4 * k4 + 2] + w.w * hh[4 * k4 + 3];
    }
    psum[tid] = acc;
    __syncthreads();
    if (tid < BINS)
        out[b * BINS + tid] = fmaxf(psum[tid] + psum[tid + BINS] + bias[tid], 0.0f);
}

// ---- fallback (ws too small): R1 atomic path, proven ----

__global__ __launch_bounds__(THREADS) void hist_atomic(const float* __restrict__ x,
                                                       unsigned int* __restrict__ ghist) {
    __shared__ unsigned int lh[WAVES][BINS];
    const int bid = blockIdx.x, tid = threadIdx.x, wave = tid >> 6;
    const int slice = bid / CHUNKS;
    for (int i = tid; i < WAVES * BINS; i += THREADS)
        ((unsigned int*)lh)[i] = 0u;
    __syncthreads();
    const float4* __restrict__ x4 = (const float4*)x;
    const int n4 = CHUNK_ELEMS >> 2, base4 = bid * n4;
#pragma unroll 4
    for (int i = tid; i < n4; i += THREADS) {
        float4 v = x4[base4 + i];
        float vv[4] = {v.x, v.y, v.z, v.w};
#pragma unroll
        for (int j = 0; j < 4; ++j) {
            float f = vv[j];
            if (f >= 0.0f && f <= 1.0f) {
                int idx = (int)(f * (float)BINS);
                if (idx > BINS - 1) idx = BINS - 1;
                atomicAdd(&lh[wave][idx], 1u);
            }
        }
    }
    __syncthreads();
    if (tid < BINS) {
        unsigned int s = lh[0][tid] + lh[1][tid] + lh[2][tid] + lh[3][tid];
        atomicAdd(&ghist[slice * BINS + tid], s);
    }
}

__global__ __launch_bounds__(128) void gemm_atomic(const unsigned int* __restrict__ ghist,
                                                   const float* __restrict__ W,
                                                   const float* __restrict__ bias,
                                                   float* __restrict__ out) {
    const int b = blockIdx.x, n = threadIdx.x;
    __shared__ float h[3 * BINS];
    const float inv = 1.0f / (float)SLICE_ELEMS;
    for (int k = n; k < 3 * BINS; k += 128)
        h[k] = (float)ghist[b * 3 * BINS + k] * inv;
    __syncthreads();
    float acc = bias[n];
    const float4* __restrict__ Wr = (const float4*)(W + n * 3 * BINS);
#pragma unroll 8
    for (int k4 = 0; k4 < 96; ++k4) {
        float4 w = Wr[k4];
        acc += w.x * h[4 * k4 + 0] + w.y * h[4 * k4 + 1] +
               w.z * h[4 * k4 + 2] + w.w * h[4 * k4 + 3];
    }
    out[b * 128 + n] = fmaxf(acc, 0.0f);
}

extern "C" void kernel_launch(void* const* d_in, const int* in_sizes, int n_in,
                              void* d_out, int out_size, void* d_ws, size_t ws_size,
                              hipStream_t stream) {
    const float* x    = (const float*)d_in[0];
    const float* W    = (const float*)d_in[1];
    const float* bias = (const float*)d_in[2];
    float* out        = (float*)d_out;

    const size_t part_bytes = (size_t)TOTAL_BLOCKS * BINS * sizeof(unsigned int); // 786 KB
    if (ws_size >= part_bytes) {
        unsigned int* part = (unsigned int*)d_ws;
        hist_part<<<TOTAL_BLOCKS, THREADS, 0, stream>>>(x, part);
        reduce_gemm<<<64, THREADS, 0, stream>>>(part, W, bias, out);
    } else {
        unsigned int* ghist = (unsigned int*)d_ws;  // 96 KB
        hipMemsetAsync(ghist, 0, NSLICE * BINS * sizeof(unsigned int), stream);
        hist_atomic<<<TOTAL_BLOCKS, THREADS, 0, stream>>>(x, ghist);
        gemm_atomic<<<64, 128, 0, stream>>>(ghist, W, bias, out);
    }
}

// Round 5
// 38.994 us; speedup vs baseline: 9.4721x; 1.0716x over previous
//
#include <hip/hip_runtime.h>

// x: [64, 3, 512, 512] f32. Per (b,c) slice: 128-bin histogram over [0,1]
// (torch.histc semantics), normalized by 512*512. feats [64,384] @ W^T + b,
// relu. W: [128,384], b: [128], out: [64,128] f32.
//
// Two dispatches (R3 showed per-block agent-scope fences cost ~400us on
// 8-XCD CDNA4 — the kernel boundary IS the cheap cross-block flush):
//   1) hist_part: 1536 blocks (6/CU, co-resident), per-wave LDS atomic
//      histograms; epilogue packs two u16 counts per u32 (max count 32768
//      fits), plain store to block-owned slot — no zeroing across replays.
//   2) reduce_gemm: 128 blocks = (b, 64-output group), 256 thr, split-k=4;
//      unpack+sum 8 partials/slice, normalize, dot with W, +bias, relu.

#define BINS 128
#define NSLICE 192                 // B*C
#define SLICE_ELEMS 262144         // 512*512
#define CHUNKS 8
#define CHUNK_ELEMS (SLICE_ELEMS / CHUNKS)   // 32768
#define THREADS 256
#define WAVES 4
#define TOTAL_BLOCKS (NSLICE * CHUNKS)       // 1536

__global__ __launch_bounds__(THREADS) void hist_part(const float* __restrict__ x,
                                                     unsigned int* __restrict__ part32) {
    __shared__ unsigned int lh[WAVES][BINS];

    const int bid  = blockIdx.x;           // slice*CHUNKS + chunk
    const int tid  = threadIdx.x;
    const int wave = tid >> 6;

    for (int i = tid; i < WAVES * BINS; i += THREADS)
        ((unsigned int*)lh)[i] = 0u;
    __syncthreads();

    const float4* __restrict__ x4 = (const float4*)x;
    const int n4    = CHUNK_ELEMS >> 2;    // 8192 float4 per chunk
    const int base4 = bid * n4;
#pragma unroll 8
    for (int i = tid; i < n4; i += THREADS) {   // 32 iters/thread
        float4 v = x4[base4 + i];
        float vv[4] = {v.x, v.y, v.z, v.w};
#pragma unroll
        for (int j = 0; j < 4; ++j) {
            float f = vv[j];
            if (f >= 0.0f && f <= 1.0f) {
                int idx = (int)(f * (float)BINS);   // exact pow2 mul; trunc==floor
                if (idx > BINS - 1) idx = BINS - 1; // f==1.0 -> last bin
                atomicAdd(&lh[wave][idx], 1u);
            }
        }
    }
    __syncthreads();

    // pack bins (2t, 2t+1) as u16 pair; uint2 reads keep banks conflict-light
    if (tid < BINS / 2) {
        uint2 a0 = ((const uint2*)lh[0])[tid];
        uint2 a1 = ((const uint2*)lh[1])[tid];
        uint2 a2 = ((const uint2*)lh[2])[tid];
        uint2 a3 = ((const uint2*)lh[3])[tid];
        unsigned int s0 = a0.x + a1.x + a2.x + a3.x;      // <= 32768
        unsigned int s1 = a0.y + a1.y + a2.y + a3.y;
        part32[bid * (BINS / 2) + tid] = s0 | (s1 << 16); // block-owned slot
    }
}

__global__ __launch_bounds__(THREADS) void reduce_gemm(const unsigned int* __restrict__ part32,
                                                       const float* __restrict__ W,
                                                       const float* __restrict__ bias,
                                                       float* __restrict__ out) {
    const int b   = blockIdx.x >> 1;       // 0..63
    const int g   = blockIdx.x & 1;        // output group: rows g*64..g*64+63
    const int tid = threadIdx.x;           // 0..255

    __shared__ float h[3 * BINS];          // 384
    __shared__ float psum[THREADS];        // 256

    const float inv = 1.0f / (float)SLICE_ELEMS;
    if (tid < 192) {                       // one u16-pair column each
        const int slice = b * 3 + (tid >> 6);
        const int pi    = tid & 63;
        const unsigned int* __restrict__ p =
            part32 + (size_t)slice * CHUNKS * (BINS / 2) + pi;
        unsigned int s0 = 0, s1 = 0;
#pragma unroll
        for (int c = 0; c < CHUNKS; ++c) {
            unsigned int u = p[c * (BINS / 2)];   // lanes consecutive -> coalesced
            s0 += u & 0xFFFFu;
            s1 += u >> 16;
        }
        h[2 * tid]     = (float)s0 * inv;
        h[2 * tid + 1] = (float)s1 * inv;
    }
    __syncthreads();

    const int o = tid & 63;                // output within group
    const int q = tid >> 6;                // split-k quarter (96 floats each)
    const int n = g * 64 + o;              // W row / output col
    float acc = 0.0f;
    const float4* __restrict__ Wr = (const float4*)(W + n * 3 * BINS + q * 96);
    const float* __restrict__ hh  = h + q * 96;
#pragma unroll
    for (int k4 = 0; k4 < 24; ++k4) {
        float4 w = Wr[k4];
        acc += w.x * hh[4 * k4 + 0] + w.y * hh[4 * k4 + 1] +
               w.z * hh[4 * k4 + 2] + w.w * hh[4 * k4 + 3];
    }
    psum[tid] = acc;
    __syncthreads();
    if (tid < 64)
        out[b * BINS + n] = fmaxf(psum[o] + psum[64 + o] + psum[128 + o] +
                                  psum[192 + o] + bias[n], 0.0f);
}

// ---- fallback (ws too small): R1 atomic path, proven ----

__global__ __launch_bounds__(THREADS) void hist_atomic(const float* __restrict__ x,
                                                       unsigned int* __restrict__ ghist) {
    __shared__ unsigned int lh[WAVES][BINS];
    const int bid = blockIdx.x, tid = threadIdx.x, wave = tid >> 6;
    const int slice = bid / CHUNKS;
    for (int i = tid; i < WAVES * BINS; i += THREADS)
        ((unsigned int*)lh)[i] = 0u;
    __syncthreads();
    const float4* __restrict__ x4 = (const float4*)x;
    const int n4 = CHUNK_ELEMS >> 2, base4 = bid * n4;
#pragma unroll 4
    for (int i = tid; i < n4; i += THREADS) {
        float4 v = x4[base4 + i];
        float vv[4] = {v.x, v.y, v.z, v.w};
#pragma unroll
        for (int j = 0; j < 4; ++j) {
            float f = vv[j];
            if (f >= 0.0f && f <= 1.0f) {
                int idx = (int)(f * (float)BINS);
                if (idx > BINS - 1) idx = BINS - 1;
                atomicAdd(&lh[wave][idx], 1u);
            }
        }
    }
    __syncthreads();
    if (tid < BINS) {
        unsigned int s = lh[0][tid] + lh[1][tid] + lh[2][tid] + lh[3][tid];
        atomicAdd(&ghist[slice * BINS + tid], s);
    }
}

__global__ __launch_bounds__(128) void gemm_atomic(const unsigned int* __restrict__ ghist,
                                                   const float* __restrict__ W,
                                                   const float* __restrict__ bias,
                                                   float* __restrict__ out) {
    const int b = blockIdx.x, n = threadIdx.x;
    __shared__ float h[3 * BINS];
    const float inv = 1.0f / (float)SLICE_ELEMS;
    for (int k = n; k < 3 * BINS; k += 128)
        h[k] = (float)ghist[b * 3 * BINS + k] * inv;
    __syncthreads();
    float acc = bias[n];
    const float4* __restrict__ Wr = (const float4*)(W + n * 3 * BINS);
#pragma unroll 8
    for (int k4 = 0; k4 < 96; ++k4) {
        float4 w = Wr[k4];
        acc += w.x * h[4 * k4 + 0] + w.y * h[4 * k4 + 1] +
               w.z * h[4 * k4 + 2] + w.w * h[4 * k4 + 3];
    }
    out[b * 128 + n] = fmaxf(acc, 0.0f);
}

extern "C" void kernel_launch(void* const* d_in, const int* in_sizes, int n_in,
                              void* d_out, int out_size, void* d_ws, size_t ws_size,
                              hipStream_t stream) {
    const float* x    = (const float*)d_in[0];
    const float* W    = (const float*)d_in[1];
    const float* bias = (const float*)d_in[2];
    float* out        = (float*)d_out;

    const size_t part_bytes = (size_t)TOTAL_BLOCKS * (BINS / 2) * sizeof(unsigned int); // 393 KB
    if (ws_size >= part_bytes) {
        unsigned int* part32 = (unsigned int*)d_ws;
        hist_part<<<TOTAL_BLOCKS, THREADS, 0, stream>>>(x, part32);
        reduce_gemm<<<128, THREADS, 0, stream>>>(part32, W, bias, out);
    } else {
        unsigned int* ghist = (unsigned int*)d_ws;  // 96 KB
        hipMemsetAsync(ghist, 0, NSLICE * BINS * sizeof(unsigned int), stream);
        hist_atomic<<<TOTAL_BLOCKS, THREADS, 0, stream>>>(x, ghist);
        gemm_atomic<<<64, 128, 0, stream>>>(ghist, W, bias, out);
    }
}